// Round 11
// baseline (345.682 us; speedup 1.0000x reference)
//
#include <hip/hip_runtime.h>
#include <math.h>

// ---------------------------------------------------------------------------
// GAT (3-layer, PyG GATConv semantics) on MI355X.
// Round 11: gather-latency attack.
//   - agg_sm512: 2 waves per node split the edge list (stride-2) -> serial
//     gather chain halves; LDS merge; wave0 epilogue+pack-write.
//   - agg_final240_sm: lane->-(head,4ch) remap: one uint2 load per edge
//     (was six 2B loads), LDS head-merge for the mean.
// Everything else unchanged from round 10 (13 dispatches, fused MFMA GEMM).
// ---------------------------------------------------------------------------

#define N_FEAT 256
#define HID 512

using u16 = unsigned short;
using bf16x8 = __attribute__((ext_vector_type(8))) __bf16;
using f32x16 = __attribute__((ext_vector_type(16))) float;

__device__ inline u16 bf16_rne(float f) {
    unsigned u = __float_as_uint(f);
    return (u16)((u + 0x7fffu + ((u >> 16) & 1u)) >> 16);
}
__device__ inline float bf16_to_f32(u16 h) {
    return __uint_as_float((unsigned)h << 16);
}
__device__ inline bf16x8 ldb8(const u16* p) {
    return *reinterpret_cast<const bf16x8*>(p);
}
__device__ inline void acc8(float a, const uint4 r, float* acc) {
    acc[0] = fmaf(a, __uint_as_float(r.x << 16), acc[0]);
    acc[1] = fmaf(a, __uint_as_float(r.x & 0xffff0000u), acc[1]);
    acc[2] = fmaf(a, __uint_as_float(r.y << 16), acc[2]);
    acc[3] = fmaf(a, __uint_as_float(r.y & 0xffff0000u), acc[3]);
    acc[4] = fmaf(a, __uint_as_float(r.z << 16), acc[4]);
    acc[5] = fmaf(a, __uint_as_float(r.z & 0xffff0000u), acc[5]);
    acc[6] = fmaf(a, __uint_as_float(r.w << 16), acc[6]);
    acc[7] = fmaf(a, __uint_as_float(r.w & 0xffff0000u), acc[7]);
}

// ---------------- CSR construction ----------------

__global__ void init_counts(int* cursor, int N) {
    int i = blockIdx.x * blockDim.x + threadIdx.x;
    if (i < N) cursor[i] = 1;  // self loop contributes 1
}

__global__ void count_edges(const int* __restrict__ ei, int E, int* cursor) {
    int e = blockIdx.x * blockDim.x + threadIdx.x;
    if (e < E) atomicAdd(&cursor[ei[E + e]], 1);
}

__global__ __launch_bounds__(1024) void scan_offsets(int* cursor, int* row_off, int N) {
    __shared__ int sdata[1024];
    int tid = threadIdx.x;
    int chunk = (N + 1023) >> 10;
    int base = tid * chunk;
    int lsum = 0;
    for (int i = 0; i < chunk; i++) {
        int idx = base + i;
        if (idx < N) lsum += cursor[idx];
    }
    sdata[tid] = lsum;
    __syncthreads();
    for (int off = 1; off < 1024; off <<= 1) {
        int t = (tid >= off) ? sdata[tid - off] : 0;
        __syncthreads();
        sdata[tid] += t;
        __syncthreads();
    }
    int run = sdata[tid] - lsum;
    if (tid == 0) row_off[0] = 0;
    for (int i = 0; i < chunk; i++) {
        int idx = base + i;
        if (idx < N) {
            int c = cursor[idx];
            cursor[idx] = run;
            run += c;
            row_off[idx + 1] = run;
        }
    }
}

__global__ void fill_csr(const int* __restrict__ ei, int E, int N,
                         int* cursor, int* __restrict__ col) {
    int i = blockIdx.x * blockDim.x + threadIdx.x;
    int tot = E + N;
    if (i >= tot) return;
    int s, d;
    if (i < E) { s = ei[i]; d = ei[E + i]; }
    else       { s = i - E; d = s; }
    int pos = atomicAdd(&cursor[d], 1);
    col[pos] = s;
}

// ---------------- attention col combine (all 3 layers, one launch) -------

__global__ __launch_bounds__(256) void att_combine_all(
        const float* __restrict__ W0, const float* __restrict__ as0, const float* __restrict__ ad0,
        const float* __restrict__ W1, const float* __restrict__ as1, const float* __restrict__ ad1,
        const float* __restrict__ W2, const float* __restrict__ as2, const float* __restrict__ ad2,
        float* __restrict__ ac0, float* __restrict__ ac1, float* __restrict__ ac2) {
    int i = blockIdx.x * blockDim.x + threadIdx.x;
    const float *W, *as_, *ad_;
    float* ac;
    int K, H, C, li;
    if (i < 2048)       { W = W0; as_ = as0; ad_ = ad0; ac = ac0; K = 256; H = 4; C = 128; li = i; }
    else if (i < 6144)  { W = W1; as_ = as1; ad_ = ad1; ac = ac1; K = 512; H = 4; C = 128; li = i - 2048; }
    else if (i < 12288) { W = W2; as_ = as2; ad_ = ad2; ac = ac2; K = 512; H = 6; C = 40;  li = i - 6144; }
    else return;
    int k = li / (2 * H);
    int hh = li - k * 2 * H;
    int h = (hh >= H) ? hh - H : hh;
    const float* av = ((hh >= H) ? ad_ : as_) + h * C;
    const float* wp = W + (size_t)k * H * C + (size_t)h * C;
    float sum = 0.f;
    for (int c = 0; c < C; c++) sum = fmaf(wp[c], av[c], sum);
    ac[(size_t)k * 2 * H + hh] = sum;
}

// ---------------- split-bf16 packing ----------------

__global__ __launch_bounds__(256) void cvtA_pack(const float* __restrict__ X,
                                                 u16* __restrict__ hi, u16* __restrict__ lo,
                                                 int M, int K, int Rblocks) {
    int gid = blockIdx.x * blockDim.x + threadIdx.x;
    int lane = gid & 63;
    int rest = gid >> 6;                 // R * KC + c
    int KC = K >> 4;
    int R = rest / KC;
    int c = rest - R * KC;
    if (R >= Rblocks) return;
    int row = R * 32 + (lane & 31);
    if (row >= M) row = M - 1;           // clamp: clamped rows never stored
    const float* src = X + (size_t)row * K + c * 16 + (lane >> 5) * 8;
    float4 v0 = *reinterpret_cast<const float4*>(src);
    float4 v1 = *reinterpret_cast<const float4*>(src + 4);
    float vv[8] = {v0.x, v0.y, v0.z, v0.w, v1.x, v1.y, v1.z, v1.w};
    unsigned hp[4], lp[4];
    #pragma unroll
    for (int j = 0; j < 4; j++) {
        u16 h0 = bf16_rne(vv[2 * j]);
        u16 h1 = bf16_rne(vv[2 * j + 1]);
        float r0 = vv[2 * j]     - __uint_as_float((unsigned)h0 << 16);
        float r1 = vv[2 * j + 1] - __uint_as_float((unsigned)h1 << 16);
        u16 l0 = bf16_rne(r0);
        u16 l1 = bf16_rne(r1);
        hp[j] = (unsigned)h0 | ((unsigned)h1 << 16);
        lp[j] = (unsigned)l0 | ((unsigned)l1 << 16);
    }
    size_t dst = ((size_t)rest * 64 + lane) * 8;
    *reinterpret_cast<int4*>(hi + dst) = make_int4(hp[0], hp[1], hp[2], hp[3]);
    *reinterpret_cast<int4*>(lo + dst) = make_int4(lp[0], lp[1], lp[2], lp[3]);
}

__device__ inline void cvtB_body(const float* __restrict__ B,
                                 u16* __restrict__ hi, u16* __restrict__ lo,
                                 int K, int Nb, int gid) {
    int lane = gid & 63;
    int rest = gid >> 6;                 // Cb * KC + c
    int KC = K >> 4;
    int Cb = rest / KC;
    int c = rest - Cb * KC;
    int n = Cb * 32 + (lane & 31);
    int kbase = c * 16 + (lane >> 5) * 8;
    float vv[8];
    #pragma unroll
    for (int j = 0; j < 8; j++)
        vv[j] = (n < Nb) ? B[(size_t)(kbase + j) * Nb + n] : 0.f;
    unsigned hp[4], lp[4];
    #pragma unroll
    for (int j = 0; j < 4; j++) {
        u16 h0 = bf16_rne(vv[2 * j]);
        u16 h1 = bf16_rne(vv[2 * j + 1]);
        float r0 = vv[2 * j]     - __uint_as_float((unsigned)h0 << 16);
        float r1 = vv[2 * j + 1] - __uint_as_float((unsigned)h1 << 16);
        u16 l0 = bf16_rne(r0);
        u16 l1 = bf16_rne(r1);
        hp[j] = (unsigned)h0 | ((unsigned)h1 << 16);
        lp[j] = (unsigned)l0 | ((unsigned)l1 << 16);
    }
    size_t dst = ((size_t)rest * 64 + lane) * 8;
    *reinterpret_cast<int4*>(hi + dst) = make_int4(hp[0], hp[1], hp[2], hp[3]);
    *reinterpret_cast<int4*>(lo + dst) = make_int4(lp[0], lp[1], lp[2], lp[3]);
}

// L0 B (KC=16): blk 0-15 W0 | 16-31 Wskip_in | 32 ac0 | 33 zero
// L1 B (KC=32): blk 0-15 W1 | 16 ac1 | 17 zero
// L2 B (KC=32): blk 0-7 W2 | 8-9 Wskip_out | 10 ac2 | 11 zero
__global__ __launch_bounds__(256) void pack_all_B(
        const float* __restrict__ W0, const float* __restrict__ Wsi, const float* __restrict__ ac0,
        const float* __restrict__ W1, const float* __restrict__ ac1,
        const float* __restrict__ W2, const float* __restrict__ Wso, const float* __restrict__ ac2,
        u16* __restrict__ B0h, u16* __restrict__ B0l,
        u16* __restrict__ B1h, u16* __restrict__ B1l,
        u16* __restrict__ B2h, u16* __restrict__ B2l) {
    int g = blockIdx.x * blockDim.x + threadIdx.x;
    if (g < 16384)      cvtB_body(W0,  B0h, B0l, 256, 512, g);
    else if (g < 32768) cvtB_body(Wsi, B0h + (size_t)16 * 16 * 512, B0l + (size_t)16 * 16 * 512, 256, 512, g - 16384);
    else if (g < 34816) cvtB_body(ac0, B0h + (size_t)32 * 16 * 512, B0l + (size_t)32 * 16 * 512, 256, 8,   g - 32768);
    else if (g < 67584) cvtB_body(W1,  B1h, B1l, 512, 512, g - 34816);
    else if (g < 71680) cvtB_body(ac1, B1h + (size_t)16 * 32 * 512, B1l + (size_t)16 * 32 * 512, 512, 8,   g - 67584);
    else if (g < 88064) cvtB_body(W2,  B2h, B2l, 512, 240, g - 71680);
    else if (g < 92160) cvtB_body(Wso, B2h + (size_t)8 * 32 * 512,  B2l + (size_t)8 * 32 * 512,  512, 40,  g - 88064);
    else if (g < 96256) cvtB_body(ac2, B2h + (size_t)10 * 32 * 512, B2l + (size_t)10 * 32 * 512, 512, 12,  g - 92160);
}

// ---------------- fused MFMA GEMM (validated) ----------------

__global__ __launch_bounds__(256) void gemm_fused(const u16* __restrict__ Ahi,
                                                  const u16* __restrict__ Alo,
                                                  const u16* __restrict__ Bhi,
                                                  const u16* __restrict__ Blo,
                                                  u16* __restrict__ xwb, int xwCols,
                                                  float* __restrict__ skipP,
                                                  int skipBeg, int skipEnd,
                                                  float* __restrict__ asrc,
                                                  float* __restrict__ adst,
                                                  int attBeg, int H,
                                                  int M, int K,
                                                  int ntiles, int Rblocks) {
    int nwg = gridDim.x, b = blockIdx.x;
    int q = nwg >> 3, r = nwg & 7;
    int xcd = b & 7, idx = b >> 3;
    int t = (xcd < r) ? (xcd * (q + 1) + idx)
                      : (r * (q + 1) + (xcd - r) * q + idx);
    int bm = (t / ntiles) * 128;
    int bn = (t - (t / ntiles) * ntiles) * 64;

    int lane = threadIdx.x & 63, w = threadIdx.x >> 6;
    int wr = w >> 1, wc = w & 1;
    int l31 = lane & 31, lg = lane >> 5;
    int KC = K >> 4;

    int R0 = (bm + wr * 64) >> 5;
    int R1 = R0 + 1;
    if (R0 >= Rblocks) R0 = Rblocks - 1;
    if (R1 >= Rblocks) R1 = Rblocks - 1;
    int Cb = (bn + wc * 32) >> 5;

    const u16* pa0h = Ahi + (((size_t)R0 * KC) * 64 + lane) * 8;
    const u16* pa0l = Alo + (((size_t)R0 * KC) * 64 + lane) * 8;
    const u16* pa1h = Ahi + (((size_t)R1 * KC) * 64 + lane) * 8;
    const u16* pa1l = Alo + (((size_t)R1 * KC) * 64 + lane) * 8;
    const u16* pbh  = Bhi + (((size_t)Cb * KC) * 64 + lane) * 8;
    const u16* pbl  = Blo + (((size_t)Cb * KC) * 64 + lane) * 8;

    f32x16 acc0, acc1;
    #pragma unroll
    for (int i2 = 0; i2 < 16; i2++) { acc0[i2] = 0.f; acc1[i2] = 0.f; }

    bf16x8 a0h = ldb8(pa0h), a0l = ldb8(pa0l);
    bf16x8 a1h = ldb8(pa1h), a1l = ldb8(pa1l);
    bf16x8 bh  = ldb8(pbh),  bl  = ldb8(pbl);

    for (int c = 1; c <= KC; c++) {
        size_t off = (size_t)c * 512;
        bf16x8 na0h = ldb8(pa0h + off), na0l = ldb8(pa0l + off);
        bf16x8 na1h = ldb8(pa1h + off), na1l = ldb8(pa1l + off);
        bf16x8 nbh  = ldb8(pbh + off),  nbl  = ldb8(pbl + off);
        acc0 = __builtin_amdgcn_mfma_f32_32x32x16_bf16(a0h, bh, acc0, 0, 0, 0);
        acc1 = __builtin_amdgcn_mfma_f32_32x32x16_bf16(a1h, bh, acc1, 0, 0, 0);
        acc0 = __builtin_amdgcn_mfma_f32_32x32x16_bf16(a0h, bl, acc0, 0, 0, 0);
        acc1 = __builtin_amdgcn_mfma_f32_32x32x16_bf16(a1h, bl, acc1, 0, 0, 0);
        acc0 = __builtin_amdgcn_mfma_f32_32x32x16_bf16(a0l, bh, acc0, 0, 0, 0);
        acc1 = __builtin_amdgcn_mfma_f32_32x32x16_bf16(a1l, bh, acc1, 0, 0, 0);
        a0h = na0h; a0l = na0l; a1h = na1h; a1l = na1l; bh = nbh; bl = nbl;
    }

    int n = bn + wc * 32 + l31;
    int base_m = bm + wr * 64;
    #pragma unroll
    for (int rg = 0; rg < 16; rg++) {
        int mrow = (rg & 3) + 8 * (rg >> 2) + 4 * lg;
        int m0 = base_m + mrow;
        int m1 = m0 + 32;
        float v0 = acc0[rg], v1 = acc1[rg];
        if (n < xwCols) {
            if (m0 < M) xwb[(size_t)m0 * xwCols + n] = bf16_rne(v0);
            if (m1 < M) xwb[(size_t)m1 * xwCols + n] = bf16_rne(v1);
        } else if (n >= skipBeg && n < skipEnd) {
            int cc = n - skipBeg, st = skipEnd - skipBeg;
            if (m0 < M) skipP[(size_t)m0 * st + cc] = v0;
            if (m1 < M) skipP[(size_t)m1 * st + cc] = v1;
        } else if (n >= attBeg && n < attBeg + H) {
            int h = n - attBeg;
            if (m0 < M) asrc[(size_t)m0 * H + h] = v0;
            if (m1 < M) asrc[(size_t)m1 * H + h] = v1;
        } else if (n >= attBeg + H && n < attBeg + 2 * H) {
            int h = n - attBeg - H;
            if (m0 < M) adst[(size_t)m0 * H + h] = v0;
            if (m1 < M) adst[(size_t)m1 * H + h] = v1;
        }
    }
}

// ---------------- fused softmax + aggregation, H=4, C=128 ----------------
// Block = 2 nodes x 2 waves. Both waves of a pair compute softmax stats
// (redundant, identical bits); each wave gathers edges j==half (mod 2);
// LDS merge; wave0 epilogue: elu(+bias+skip) -> packed hi/lo A-fragments.

template <int SKIPPK>
__global__ __launch_bounds__(256) void agg_sm512(const u16* __restrict__ xw,
                                                 const float* __restrict__ asrc,
                                                 const float* __restrict__ adst,
                                                 const int* __restrict__ row_off,
                                                 const int* __restrict__ col,
                                                 const float* __restrict__ bias,
                                                 const float* __restrict__ skipF,
                                                 const u16* __restrict__ skipHi,
                                                 const u16* __restrict__ skipLo,
                                                 u16* __restrict__ outHi,
                                                 u16* __restrict__ outLo,
                                                 int N) {
    __shared__ float lalpha[2][256 * 4];
    __shared__ int   lcol[2][256];
    __shared__ float lmerge[2][512];
    int tid = threadIdx.x;
    int widx = tid >> 6;            // 0..3
    int p = widx >> 1;              // node slot in block
    int half = widx & 1;            // edge parity this wave gathers
    int lane = tid & 63;
    int w = blockIdx.x * 2 + p;     // node
    bool valid = w < N;
    int jb = 0, je = 0;
    float adn[4], m[4], inv[4];

    if (valid) {
        jb = row_off[w]; je = row_off[w + 1];
        float4 ad4 = *reinterpret_cast<const float4*>(&adst[(size_t)w * 4]);
        adn[0] = ad4.x; adn[1] = ad4.y; adn[2] = ad4.z; adn[3] = ad4.w;

        float ev[4][4];
        int scol[4];
        #pragma unroll
        for (int h = 0; h < 4; h++) m[h] = -INFINITY;

        #pragma unroll
        for (int c = 0; c < 4; c++) {
            int j = jb + c * 64 + lane;
            if (j < je) {
                int s = col[j]; scol[c] = s;
                float4 as4 = *reinterpret_cast<const float4*>(&asrc[(size_t)s * 4]);
                float e0 = as4.x + adn[0]; e0 = e0 > 0.f ? e0 : 0.2f * e0;
                float e1 = as4.y + adn[1]; e1 = e1 > 0.f ? e1 : 0.2f * e1;
                float e2 = as4.z + adn[2]; e2 = e2 > 0.f ? e2 : 0.2f * e2;
                float e3 = as4.w + adn[3]; e3 = e3 > 0.f ? e3 : 0.2f * e3;
                ev[c][0] = e0; ev[c][1] = e1; ev[c][2] = e2; ev[c][3] = e3;
                m[0] = fmaxf(m[0], e0); m[1] = fmaxf(m[1], e1);
                m[2] = fmaxf(m[2], e2); m[3] = fmaxf(m[3], e3);
            } else {
                scol[c] = -1;
                #pragma unroll
                for (int h = 0; h < 4; h++) ev[c][h] = -INFINITY;
            }
        }
        for (int j = jb + 256 + lane; j < je; j += 64) {   // deg>256 fallback
            int s = col[j];
            #pragma unroll
            for (int h = 0; h < 4; h++) {
                float e = asrc[(size_t)s * 4 + h] + adn[h];
                e = e > 0.f ? e : 0.2f * e;
                m[h] = fmaxf(m[h], e);
            }
        }
        #pragma unroll
        for (int off = 32; off; off >>= 1)
            #pragma unroll
            for (int h = 0; h < 4; h++) m[h] = fmaxf(m[h], __shfl_xor(m[h], off));

        float ssum[4] = {0.f, 0.f, 0.f, 0.f};
        #pragma unroll
        for (int c = 0; c < 4; c++)
            #pragma unroll
            for (int h = 0; h < 4; h++) ssum[h] += __expf(ev[c][h] - m[h]);
        for (int j = jb + 256 + lane; j < je; j += 64) {
            int s = col[j];
            #pragma unroll
            for (int h = 0; h < 4; h++) {
                float e = asrc[(size_t)s * 4 + h] + adn[h];
                e = e > 0.f ? e : 0.2f * e;
                ssum[h] += __expf(e - m[h]);
            }
        }
        #pragma unroll
        for (int off = 32; off; off >>= 1)
            #pragma unroll
            for (int h = 0; h < 4; h++) ssum[h] += __shfl_xor(ssum[h], off);
        #pragma unroll
        for (int h = 0; h < 4; h++) inv[h] = 1.f / (ssum[h] + 1e-16f);

        // both waves write identical values (benign)
        #pragma unroll
        for (int c = 0; c < 4; c++) {
            int rel = c * 64 + lane;
            if (jb + rel < je) {
                lcol[p][rel] = scol[c];
                *reinterpret_cast<float4*>(&lalpha[p][rel * 4]) = make_float4(
                    __expf(ev[c][0] - m[0]) * inv[0],
                    __expf(ev[c][1] - m[1]) * inv[1],
                    __expf(ev[c][2] - m[2]) * inv[2],
                    __expf(ev[c][3] - m[3]) * inv[3]);
            }
        }
    }
    __syncthreads();

    int base = lane * 8;
    int hme = lane >> 4;
    float acc[8] = {};
    int deg = je - jb;
    int fast = deg < 256 ? deg : 256;

    if (valid) {
        int j = half;
        for (; j + 6 < fast; j += 8) {              // 4 stride-2 gathers in flight
            int s0 = lcol[p][j],     s1 = lcol[p][j + 2];
            int s2 = lcol[p][j + 4], s3 = lcol[p][j + 6];
            float a0 = lalpha[p][(j + 0) * 4 + hme];
            float a1 = lalpha[p][(j + 2) * 4 + hme];
            float a2 = lalpha[p][(j + 4) * 4 + hme];
            float a3 = lalpha[p][(j + 6) * 4 + hme];
            uint4 r0 = *reinterpret_cast<const uint4*>(&xw[(size_t)s0 * 512 + base]);
            uint4 r1 = *reinterpret_cast<const uint4*>(&xw[(size_t)s1 * 512 + base]);
            uint4 r2 = *reinterpret_cast<const uint4*>(&xw[(size_t)s2 * 512 + base]);
            uint4 r3 = *reinterpret_cast<const uint4*>(&xw[(size_t)s3 * 512 + base]);
            acc8(a0, r0, acc); acc8(a1, r1, acc);
            acc8(a2, r2, acc); acc8(a3, r3, acc);
        }
        for (; j < fast; j += 2) {
            int s = lcol[p][j];
            float a = lalpha[p][j * 4 + hme];
            uint4 raw = *reinterpret_cast<const uint4*>(&xw[(size_t)s * 512 + base]);
            acc8(a, raw, acc);
        }
        if (deg > 256 && half == 0) {   // slow fallback, never taken at scale
            for (int jj = jb + 256; jj < je; ++jj) {
                int s = col[jj];
                float e = asrc[(size_t)s * 4 + hme] + adn[hme];
                e = e > 0.f ? e : 0.2f * e;
                float a = __expf(e - m[hme]) * inv[hme];
                uint4 raw = *reinterpret_cast<const uint4*>(&xw[(size_t)s * 512 + base]);
                acc8(a, raw, acc);
            }
        }
        if (half == 1) {
            *reinterpret_cast<float4*>(&lmerge[p][base])     = make_float4(acc[0], acc[1], acc[2], acc[3]);
            *reinterpret_cast<float4*>(&lmerge[p][base + 4]) = make_float4(acc[4], acc[5], acc[6], acc[7]);
        }
    }
    __syncthreads();
    if (!valid || half == 1) return;

    {
        float4 m0 = *reinterpret_cast<const float4*>(&lmerge[p][base]);
        float4 m1 = *reinterpret_cast<const float4*>(&lmerge[p][base + 4]);
        acc[0] += m0.x; acc[1] += m0.y; acc[2] += m0.z; acc[3] += m0.w;
        acc[4] += m1.x; acc[5] += m1.y; acc[6] += m1.z; acc[7] += m1.w;
    }

    // pack-slot address for node w, channels [base, base+8), K=512 (KC=32)
    int R = w >> 5, r31 = w & 31, cc = lane >> 1, sub = lane & 1;
    int lp = r31 | (sub << 5);
    size_t slot = (((size_t)R * 32 + cc) * 64 + lp) * 8;

    float sk[8];
    if (SKIPPK) {
        int4 h4 = *reinterpret_cast<const int4*>(skipHi + slot);
        int4 l4 = *reinterpret_cast<const int4*>(skipLo + slot);
        unsigned hu[4] = {(unsigned)h4.x, (unsigned)h4.y, (unsigned)h4.z, (unsigned)h4.w};
        unsigned lu[4] = {(unsigned)l4.x, (unsigned)l4.y, (unsigned)l4.z, (unsigned)l4.w};
        #pragma unroll
        for (int i = 0; i < 4; i++) {
            sk[2 * i]     = __uint_as_float(hu[i] << 16) + __uint_as_float(lu[i] << 16);
            sk[2 * i + 1] = __uint_as_float(hu[i] & 0xffff0000u)
                          + __uint_as_float(lu[i] & 0xffff0000u);
        }
    } else {
        const float* kp = &skipF[(size_t)w * 512 + base];
        float4 s0 = *reinterpret_cast<const float4*>(kp);
        float4 s1 = *reinterpret_cast<const float4*>(kp + 4);
        sk[0] = s0.x; sk[1] = s0.y; sk[2] = s0.z; sk[3] = s0.w;
        sk[4] = s1.x; sk[5] = s1.y; sk[6] = s1.z; sk[7] = s1.w;
    }

    const float* bp = &bias[base];
    float r[8];
    #pragma unroll
    for (int i = 0; i < 8; i++) {
        float v = acc[i] + bp[i] + sk[i];
        r[i] = v > 0.f ? v : expm1f(v);          // elu
    }

    unsigned hp[4], lpk[4];
    #pragma unroll
    for (int i = 0; i < 4; i++) {
        u16 h0 = bf16_rne(r[2 * i]);
        u16 h1 = bf16_rne(r[2 * i + 1]);
        float q0 = r[2 * i]     - __uint_as_float((unsigned)h0 << 16);
        float q1 = r[2 * i + 1] - __uint_as_float((unsigned)h1 << 16);
        u16 l0 = bf16_rne(q0);
        u16 l1 = bf16_rne(q1);
        hp[i]  = (unsigned)h0 | ((unsigned)h1 << 16);
        lpk[i] = (unsigned)l0 | ((unsigned)l1 << 16);
    }
    *reinterpret_cast<int4*>(outHi + slot) = make_int4(hp[0], hp[1], hp[2], hp[3]);
    *reinterpret_cast<int4*>(outLo + slot) = make_int4(lpk[0], lpk[1], lpk[2], lpk[3]);
}

// ---------------- fused softmax + aggregation, layer 2 (H=6, C=40) -------
// Lane remap: lane l<60 -> head h=l/10, cols 4*(l%10)..+3 -> ONE uint2 load
// per edge. LDS head-merge, then lanes 0..39 do mean + bias + skip.

__global__ __launch_bounds__(256) void agg_final240_sm(const u16* __restrict__ xw,
                                                       const float* __restrict__ asrc,
                                                       const float* __restrict__ adst,
                                                       const int* __restrict__ row_off,
                                                       const int* __restrict__ col,
                                                       const float* __restrict__ b2,
                                                       const float* __restrict__ skip,
                                                       float* __restrict__ out,
                                                       int N) {
    __shared__ float lalpha[4][256 * 6];
    __shared__ int   lcol[4][256];
    __shared__ float lmerge[4][240];
    int w = (blockIdx.x * blockDim.x + threadIdx.x) >> 6;
    int lane = threadIdx.x & 63;
    int wid = (threadIdx.x >> 6) & 3;
    bool valid = w < N;
    int jb = 0, je = 0;
    float adn[6], m[6], inv[6];

    if (valid) {
        jb = row_off[w]; je = row_off[w + 1];
        #pragma unroll
        for (int h = 0; h < 6; h++) adn[h] = adst[(size_t)w * 6 + h];

        float ev[4][6];
        int scol[4];
        #pragma unroll
        for (int h = 0; h < 6; h++) m[h] = -INFINITY;

        #pragma unroll
        for (int c = 0; c < 4; c++) {
            int j = jb + c * 64 + lane;
            if (j < je) {
                int s = col[j]; scol[c] = s;
                #pragma unroll
                for (int h = 0; h < 6; h++) {
                    float e = asrc[(size_t)s * 6 + h] + adn[h];
                    e = e > 0.f ? e : 0.2f * e;
                    ev[c][h] = e;
                    m[h] = fmaxf(m[h], e);
                }
            } else {
                scol[c] = -1;
                #pragma unroll
                for (int h = 0; h < 6; h++) ev[c][h] = -INFINITY;
            }
        }
        for (int j = jb + 256 + lane; j < je; j += 64) {
            int s = col[j];
            #pragma unroll
            for (int h = 0; h < 6; h++) {
                float e = asrc[(size_t)s * 6 + h] + adn[h];
                e = e > 0.f ? e : 0.2f * e;
                m[h] = fmaxf(m[h], e);
            }
        }
        #pragma unroll
        for (int off = 32; off; off >>= 1)
            #pragma unroll
            for (int h = 0; h < 6; h++) m[h] = fmaxf(m[h], __shfl_xor(m[h], off));

        float ssum[6] = {0.f, 0.f, 0.f, 0.f, 0.f, 0.f};
        #pragma unroll
        for (int c = 0; c < 4; c++)
            #pragma unroll
            for (int h = 0; h < 6; h++) ssum[h] += __expf(ev[c][h] - m[h]);
        for (int j = jb + 256 + lane; j < je; j += 64) {
            int s = col[j];
            #pragma unroll
            for (int h = 0; h < 6; h++) {
                float e = asrc[(size_t)s * 6 + h] + adn[h];
                e = e > 0.f ? e : 0.2f * e;
                ssum[h] += __expf(e - m[h]);
            }
        }
        #pragma unroll
        for (int off = 32; off; off >>= 1)
            #pragma unroll
            for (int h = 0; h < 6; h++) ssum[h] += __shfl_xor(ssum[h], off);
        #pragma unroll
        for (int h = 0; h < 6; h++) inv[h] = 1.f / (ssum[h] + 1e-16f);

        #pragma unroll
        for (int c = 0; c < 4; c++) {
            int rel = c * 64 + lane;
            if (jb + rel < je) {
                lcol[wid][rel] = scol[c];
                #pragma unroll
                for (int h = 0; h < 6; h++)
                    lalpha[wid][rel * 6 + h] = __expf(ev[c][h] - m[h]) * inv[h];
            }
        }
    }
    __syncthreads();

    // phase B: lane l<60: head h=l/10, in-head col group i=l%10
    int h60 = lane / 10;          // 0..6 (lane 60..63 -> 6, inactive)
    int i10 = lane - h60 * 10;
    bool activeB = lane < 60;
    int coff = h60 * 40 + i10 * 4;           // u16 offset in row
    float acc[4] = {};
    int deg = je - jb;
    int fast = deg < 256 ? deg : 256;

    if (valid && activeB) {
        int j = 0;
        for (; j + 3 < fast; j += 4) {
            int s0 = lcol[wid][j],     s1 = lcol[wid][j + 1];
            int s2 = lcol[wid][j + 2], s3 = lcol[wid][j + 3];
            float a0 = lalpha[wid][(j + 0) * 6 + h60];
            float a1 = lalpha[wid][(j + 1) * 6 + h60];
            float a2 = lalpha[wid][(j + 2) * 6 + h60];
            float a3 = lalpha[wid][(j + 3) * 6 + h60];
            uint2 r0 = *reinterpret_cast<const uint2*>(&xw[(size_t)s0 * 240 + coff]);
            uint2 r1 = *reinterpret_cast<const uint2*>(&xw[(size_t)s1 * 240 + coff]);
            uint2 r2 = *reinterpret_cast<const uint2*>(&xw[(size_t)s2 * 240 + coff]);
            uint2 r3 = *reinterpret_cast<const uint2*>(&xw[(size_t)s3 * 240 + coff]);
            acc[0] = fmaf(a0, __uint_as_float(r0.x << 16), acc[0]);
            acc[1] = fmaf(a0, __uint_as_float(r0.x & 0xffff0000u), acc[1]);
            acc[2] = fmaf(a0, __uint_as_float(r0.y << 16), acc[2]);
            acc[3] = fmaf(a0, __uint_as_float(r0.y & 0xffff0000u), acc[3]);
            acc[0] = fmaf(a1, __uint_as_float(r1.x << 16), acc[0]);
            acc[1] = fmaf(a1, __uint_as_float(r1.x & 0xffff0000u), acc[1]);
            acc[2] = fmaf(a1, __uint_as_float(r1.y << 16), acc[2]);
            acc[3] = fmaf(a1, __uint_as_float(r1.y & 0xffff0000u), acc[3]);
            acc[0] = fmaf(a2, __uint_as_float(r2.x << 16), acc[0]);
            acc[1] = fmaf(a2, __uint_as_float(r2.x & 0xffff0000u), acc[1]);
            acc[2] = fmaf(a2, __uint_as_float(r2.y << 16), acc[2]);
            acc[3] = fmaf(a2, __uint_as_float(r2.y & 0xffff0000u), acc[3]);
            acc[0] = fmaf(a3, __uint_as_float(r3.x << 16), acc[0]);
            acc[1] = fmaf(a3, __uint_as_float(r3.x & 0xffff0000u), acc[1]);
            acc[2] = fmaf(a3, __uint_as_float(r3.y << 16), acc[2]);
            acc[3] = fmaf(a3, __uint_as_float(r3.y & 0xffff0000u), acc[3]);
        }
        for (; j < fast; ++j) {
            int s = lcol[wid][j];
            float a = lalpha[wid][j * 6 + h60];
            uint2 raw = *reinterpret_cast<const uint2*>(&xw[(size_t)s * 240 + coff]);
            acc[0] = fmaf(a, __uint_as_float(raw.x << 16), acc[0]);
            acc[1] = fmaf(a, __uint_as_float(raw.x & 0xffff0000u), acc[1]);
            acc[2] = fmaf(a, __uint_as_float(raw.y << 16), acc[2]);
            acc[3] = fmaf(a, __uint_as_float(raw.y & 0xffff0000u), acc[3]);
        }
        if (deg > 256) {   // fallback, never taken at scale
            for (int jj = jb + 256; jj < je; ++jj) {
                int s = col[jj];
                float e = asrc[(size_t)s * 6 + h60] + adn[h60];
                e = e > 0.f ? e : 0.2f * e;
                float a = __expf(e - m[h60]) * inv[h60];
                uint2 raw = *reinterpret_cast<const uint2*>(&xw[(size_t)s * 240 + coff]);
                acc[0] = fmaf(a, __uint_as_float(raw.x << 16), acc[0]);
                acc[1] = fmaf(a, __uint_as_float(raw.x & 0xffff0000u), acc[1]);
                acc[2] = fmaf(a, __uint_as_float(raw.y << 16), acc[2]);
                acc[3] = fmaf(a, __uint_as_float(raw.y & 0xffff0000u), acc[3]);
            }
        }
        // lmerge[wid][l*4 .. l*4+3] = acc  (l*4 == h*40 + i*4)
        *reinterpret_cast<float4*>(&lmerge[wid][lane * 4]) =
            make_float4(acc[0], acc[1], acc[2], acc[3]);
    }
    __syncthreads();
    if (!valid) return;

    if (lane < 40) {
        float s = 0.f;
        #pragma unroll
        for (int h = 0; h < 6; h++) s += lmerge[wid][h * 40 + lane];
        float v = s * (1.f / 6.f) + b2[lane] + skip[(size_t)w * 40 + lane];
        out[(size_t)w * 40 + lane] = v;
    }
}

// ---------------- orchestration ----------------

extern "C" void kernel_launch(void* const* d_in, const int* in_sizes, int n_in,
                              void* d_out, int out_size, void* d_ws, size_t ws_size,
                              hipStream_t stream) {
    const float* x        = (const float*)d_in[0];
    const int*   ei       = (const int*)  d_in[1];
    const float* W0       = (const float*)d_in[2];
    const float* a_src0   = (const float*)d_in[3];
    const float* a_dst0   = (const float*)d_in[4];
    const float* b0       = (const float*)d_in[5];
    const float* Wskip_in = (const float*)d_in[6];
    const float* W1       = (const float*)d_in[7];
    const float* a_src1   = (const float*)d_in[8];
    const float* a_dst1   = (const float*)d_in[9];
    const float* b1       = (const float*)d_in[10];
    const float* W2       = (const float*)d_in[11];
    const float* a_src2   = (const float*)d_in[12];
    const float* a_dst2   = (const float*)d_in[13];
    const float* b2       = (const float*)d_in[14];
    const float* Wskip_out= (const float*)d_in[15];

    const int N = in_sizes[0] / N_FEAT;     // 10000
    const int E = in_sizes[1] / 2;          // 160000
    float* out = (float*)d_out;

    const int Rblocks = (N + 31) / 32;      // 313
    const int mtiles = (N + 127) / 128;     // 79

    // ---------- workspace layout (ws_size = 256 MiB measured) ----------
    float* ws = (float*)d_ws;
    size_t o = 0;
    u16* xwb   = (u16*)(ws + o); o += (size_t)N * 256;   // N*512 bf16
    float* tmpD  = ws + o; o += (size_t)N * HID;         // L0 skip_in (fp32)
    float* asrc  = ws + o; o += (size_t)N * 8;
    float* adst  = ws + o; o += (size_t)N * 8;
    float* skipo = ws + o; o += (size_t)N * 40;
    float* ac0   = ws + o; o += 256 * 8;
    float* ac1   = ws + o; o += 512 * 8;
    float* ac2   = ws + o; o += 512 * 12;

    u16* up = (u16*)(ws + o);
    size_t uo = 0;
    const size_t aPack = (size_t)Rblocks * 32 * 512 + 512;   // K=512 pack + guard
    u16* AhA = up + uo; uo += aPack;   u16* AlA = up + uo; uo += aPack;
    u16* AhB = up + uo; uo += aPack;   u16* AlB = up + uo; uo += aPack;
    const size_t b0sz = (size_t)34 * 16 * 512 + 512;   // L0: 34 blocks, KC=16
    u16* B0h = up + uo; uo += b0sz;  u16* B0l = up + uo; uo += b0sz;
    const size_t b1sz = (size_t)18 * 32 * 512 + 512;   // L1: 18 blocks, KC=32
    u16* B1h = up + uo; uo += b1sz;  u16* B1l = up + uo; uo += b1sz;
    const size_t b2sz = (size_t)12 * 32 * 512 + 512;   // L2: 12 blocks, KC=32
    u16* B2h = up + uo; uo += b2sz;  u16* B2l = up + uo; uo += b2sz;
    int* row_off = (int*)(up + uo);
    int* cursor  = row_off + (N + 1);
    int* col     = cursor + (N + 1);

    // ---- CSR by destination (includes self loops) ----
    init_counts<<<(N + 255) / 256, 256, 0, stream>>>(cursor, N);
    count_edges<<<(E + 255) / 256, 256, 0, stream>>>(ei, E, cursor);
    scan_offsets<<<1, 1024, 0, stream>>>(cursor, row_off, N);
    fill_csr<<<(E + N + 255) / 256, 256, 0, stream>>>(ei, E, N, cursor, col);

    // ---- combined attention columns (1 launch), then all B packs (1) ----
    att_combine_all<<<48, 256, 0, stream>>>(W0, a_src0, a_dst0,
                                            W1, a_src1, a_dst1,
                                            W2, a_src2, a_dst2, ac0, ac1, ac2);
    pack_all_B<<<376, 256, 0, stream>>>(W0, Wskip_in, ac0, W1, ac1,
                                        W2, Wskip_out, ac2,
                                        B0h, B0l, B1h, B1l, B2h, B2l);

    int pairBlocks = (N + 1) / 2;           // agg_sm512: 2 nodes / block
    int nodeBlocks = (N * 64 + 255) / 256;  // final: 4 nodes / block
    const int BIG = 1 << 30;

    // ---- Layer 0: x(fp32) -> pack -> fused GEMM (1088 cols) ----
    cvtA_pack<<<(Rblocks * 16 * 64 + 255) / 256, 256, 0, stream>>>(x, AhA, AlA, N, 256, Rblocks);
    gemm_fused<<<mtiles * 17, 256, 0, stream>>>(
        AhA, AlA, B0h, B0l, xwb, 512, tmpD, 512, 1024, asrc, adst, 1024, 4,
        N, 256, 17, Rblocks);
    agg_sm512<0><<<pairBlocks, 256, 0, stream>>>(
        xwb, asrc, adst, row_off, col, b0, tmpD, nullptr, nullptr, AhB, AlB, N);

    // ---- Layer 1: fused GEMM (576 cols), skip = x1 packs ----
    gemm_fused<<<mtiles * 9, 256, 0, stream>>>(
        AhB, AlB, B1h, B1l, xwb, 512, nullptr, BIG, BIG, asrc, adst, 512, 4,
        N, 512, 9, Rblocks);
    agg_sm512<1><<<pairBlocks, 256, 0, stream>>>(
        xwb, asrc, adst, row_off, col, b1, nullptr, AhB, AlB, AhA, AlA, N);

    // ---- Layer 2: fused GEMM (384 cols): xwb240 | skipo | att ----
    gemm_fused<<<mtiles * 6, 256, 0, stream>>>(
        AhA, AlA, B2h, B2l, xwb, 240, skipo, 256, 296, asrc, adst, 320, 6,
        N, 512, 6, Rblocks);
    agg_final240_sm<<<nodeBlocks, 256, 0, stream>>>(
        xwb, asrc, adst, row_off, col, b2, skipo, out, N);
}